// Round 1
// baseline (343.191 us; speedup 1.0000x reference)
//
#include <hip/hip_runtime.h>
#include <hip/hip_bf16.h>

typedef __attribute__((ext_vector_type(8))) short short8;
typedef __attribute__((ext_vector_type(4))) float f32x4;

constexpr int Sn = 2048, Dn = 64;
constexpr int KVB = 32;    // kv tile
constexpr int QB  = 128;   // q rows per block
constexpr int NW  = 4;     // waves per block
constexpr int KSTR = 72;   // K_lds row stride (bf16) -> 144B, breaks 32-way conflict
constexpr int VSTR = 40;   // Vt_lds row stride      -> 80B
constexpr int PSTR = 40;
constexpr float SCALE = 0.125f;             // 1/sqrt(64)
constexpr float L2E   = 1.4426950408889634f;

__device__ inline short to_bf16(float f) {
  unsigned u = __builtin_bit_cast(unsigned, f);
  u = (u + 0x7fffu + ((u >> 16) & 1u)) >> 16;   // RNE
  return (short)u;
}

__device__ inline short8 pack8(float4 a, float4 b) {
  short8 f;
  f[0]=to_bf16(a.x); f[1]=to_bf16(a.y); f[2]=to_bf16(a.z); f[3]=to_bf16(a.w);
  f[4]=to_bf16(b.x); f[5]=to_bf16(b.y); f[6]=to_bf16(b.z); f[7]=to_bf16(b.w);
  return f;
}

__global__ __launch_bounds__(256, 2)
void attn_fwd(const float* __restrict__ Qm, const float* __restrict__ Km,
              const float* __restrict__ Vm, float* __restrict__ Om) {
  __shared__ alignas(16) short K_lds[KVB][KSTR];
  __shared__ alignas(16) short Vt_lds[Dn][VSTR];
  __shared__ alignas(16) short P_lds[NW][32][PSTR];

  const int qt = blockIdx.x;       // q tile (fast-varying: same bh adjacent)
  const int bh = blockIdx.y;
  const size_t base = (size_t)bh * Sn * Dn;
  const float* Qb = Qm + base;
  const float* Kb = Km + base;
  const float* Vb = Vm + base;
  float*       Ob = Om + base;

  const int tid  = threadIdx.x;
  const int wv   = tid >> 6;
  const int lane = tid & 63;
  const int g    = lane >> 4;      // 16-lane group 0..3
  const int il   = lane & 15;

  const int qbase = qt * QB + wv * 32;

  // ---- Q fragments in registers: 2 q-subtiles x 2 d-chunks ----
  short8 qf[2][2];
  #pragma unroll
  for (int qs = 0; qs < 2; ++qs) {
    const float* qrow = Qb + (size_t)(qbase + qs*16 + il) * Dn;
    #pragma unroll
    for (int c = 0; c < 2; ++c) {
      const float4* s4 = (const float4*)(qrow + c*32 + g*8);
      qf[qs][c] = pack8(s4[0], s4[1]);
    }
  }

  float m_run[2][4], l_run[2][4];
  f32x4 acc[2][4];
  #pragma unroll
  for (int qs = 0; qs < 2; ++qs)
    #pragma unroll
    for (int r = 0; r < 4; ++r) {
      m_run[qs][r] = -1e30f; l_run[qs][r] = 0.f;
      acc[qs][r] = (f32x4){0.f,0.f,0.f,0.f};
    }

  // staging index precompute
  const int skv = tid >> 3;             // 0..31   K row
  const int sd0 = (tid & 7) * 8;        // d chunk
  const int vd  = tid & 63;             // Vt: d
  const int vk0 = (tid >> 6) * 8;       // Vt: kv chunk

  for (int kv0 = 0; kv0 < Sn; kv0 += KVB) {
    // ---- stage K (row-major bf16) and V (transposed bf16) ----
    {
      const float4* s4 = (const float4*)(Kb + (size_t)(kv0 + skv)*Dn + sd0);
      *(short8*)&K_lds[skv][sd0] = pack8(s4[0], s4[1]);
      const float* vs = Vb + (size_t)(kv0 + vk0)*Dn + vd;
      short8 h;
      #pragma unroll
      for (int j = 0; j < 8; ++j) h[j] = to_bf16(vs[(size_t)j*Dn]);
      *(short8*)&Vt_lds[vd][vk0] = h;
    }
    __syncthreads();

    // hoisted K fragments (shared across both q-subtiles)
    short8 kfr[2][2];
    #pragma unroll
    for (int t = 0; t < 2; ++t)
      #pragma unroll
      for (int c = 0; c < 2; ++c)
        kfr[t][c] = *(const short8*)&K_lds[t*16 + il][c*32 + g*8];
    // hoisted V fragments
    short8 vfr[4];
    #pragma unroll
    for (int dt = 0; dt < 4; ++dt)
      vfr[dt] = *(const short8*)&Vt_lds[dt*16 + il][g*8];

    #pragma unroll
    for (int qs = 0; qs < 2; ++qs) {
      f32x4 sa[2] = {{0.f,0.f,0.f,0.f},{0.f,0.f,0.f,0.f}};
      #pragma unroll
      for (int t = 0; t < 2; ++t)
        #pragma unroll
        for (int c = 0; c < 2; ++c)
          sa[t] = __builtin_amdgcn_mfma_f32_16x16x32_bf16(qf[qs][c], kfr[t][c], sa[t], 0, 0, 0);

      // online softmax; row q = qbase + qs*16 + g*4 + r lives at reg r of lane-group g
      #pragma unroll
      for (int r = 0; r < 4; ++r) {
        float s0 = sa[0][r]*SCALE, s1 = sa[1][r]*SCALE;
        float mx = fmaxf(s0, s1);
        mx = fmaxf(mx, __shfl_xor(mx, 1));
        mx = fmaxf(mx, __shfl_xor(mx, 2));
        mx = fmaxf(mx, __shfl_xor(mx, 4));
        mx = fmaxf(mx, __shfl_xor(mx, 8));
        float mold = m_run[qs][r];
        float mnew = fmaxf(mold, mx);
        float corr = exp2f((mold - mnew) * L2E);
        m_run[qs][r] = mnew;
        float p0 = exp2f((s0 - mnew) * L2E);
        float p1 = exp2f((s1 - mnew) * L2E);
        float rs = p0 + p1;
        rs += __shfl_xor(rs, 1);
        rs += __shfl_xor(rs, 2);
        rs += __shfl_xor(rs, 4);
        rs += __shfl_xor(rs, 8);
        l_run[qs][r] = l_run[qs][r] * corr + rs;
        #pragma unroll
        for (int dt = 0; dt < 4; ++dt) acc[qs][dt][r] *= corr;
        P_lds[wv][qs*16 + g*4 + r][il]      = to_bf16(p0);
        P_lds[wv][qs*16 + g*4 + r][16 + il] = to_bf16(p1);
      }
    }

    // ---- PV ----
    #pragma unroll
    for (int qs = 0; qs < 2; ++qs) {
      short8 pa = *(const short8*)&P_lds[wv][qs*16 + il][g*8];
      #pragma unroll
      for (int dt = 0; dt < 4; ++dt)
        acc[qs][dt] = __builtin_amdgcn_mfma_f32_16x16x32_bf16(pa, vfr[dt], acc[qs][dt], 0, 0, 0);
    }
    __syncthreads();
  }

  // ---- epilogue: O = acc / l ----
  #pragma unroll
  for (int qs = 0; qs < 2; ++qs)
    #pragma unroll
    for (int r = 0; r < 4; ++r) {
      float inv = 1.0f / l_run[qs][r];
      float* op = Ob + (size_t)(qbase + qs*16 + g*4 + r) * Dn;
      #pragma unroll
      for (int dt = 0; dt < 4; ++dt)
        op[dt*16 + il] = acc[qs][dt][r] * inv;
    }
}

extern "C" void kernel_launch(void* const* d_in, const int* in_sizes, int n_in,
                              void* d_out, int out_size, void* d_ws, size_t ws_size,
                              hipStream_t stream) {
  const float* Q = (const float*)d_in[0];
  const float* K = (const float*)d_in[1];
  const float* V = (const float*)d_in[2];
  float* O = (float*)d_out;
  dim3 grid(Sn / QB, 4 * 16);   // (q-tiles, B*H)
  attn_fwd<<<grid, 256, 0, stream>>>(Q, K, V, O);
}

// Round 2
// 107.932 us; speedup vs baseline: 3.1797x; 3.1797x over previous
//
#include <hip/hip_runtime.h>
#include <hip/hip_bf16.h>

typedef __attribute__((ext_vector_type(8))) short short8;
typedef __attribute__((ext_vector_type(4))) short short4v;
typedef __attribute__((ext_vector_type(16))) float f32x16;

constexpr int Sn = 2048, Dn = 64;
constexpr int KVB = 64;          // kv tile
constexpr int QB  = 256;         // 8 waves * 32 q rows
constexpr int NT  = Sn / KVB;    // 32 tiles
constexpr int STR = 72;          // LDS row stride in shorts; 144 B = 9*16 (b128-aligned, 2-way banks)
constexpr float QSC = 0.18033688011112042f;  // (1/sqrt(64)) * log2(e): softmax in exp2 domain

struct SMemS { short K[2][KVB][STR]; short Vt[2][Dn][STR]; };  // 36864 B
union  SMem  { SMemS s; float ep[8][32][36]; };                // epilogue scratch aliases staging

__device__ inline unsigned cvt_pk_bf16(float a, float b) {
  unsigned r;
  asm("v_cvt_pk_bf16_f32 %0, %1, %2" : "=v"(r) : "v"(a), "v"(b));
  return r;
}

__device__ inline short8 catw(unsigned w0, unsigned w1, unsigned w2, unsigned w3) {
  union { unsigned u[4]; short8 s; } t;
  t.u[0] = w0; t.u[1] = w1; t.u[2] = w2; t.u[3] = w3;
  return t.s;
}

__device__ inline short8 pack8(float4 a, float4 b) {
  return catw(cvt_pk_bf16(a.x, a.y), cvt_pk_bf16(a.z, a.w),
              cvt_pk_bf16(b.x, b.y), cvt_pk_bf16(b.z, b.w));
}

__device__ inline short8 cat4(short4v a, short4v b) {
  short8 r;
  r[0]=a[0]; r[1]=a[1]; r[2]=a[2]; r[3]=a[3];
  r[4]=b[0]; r[5]=b[1]; r[6]=b[2]; r[7]=b[3];
  return r;
}

__global__ __launch_bounds__(512)
void attn_fwd(const float* __restrict__ Qm, const float* __restrict__ Km,
              const float* __restrict__ Vm, float* __restrict__ Om) {
  __shared__ alignas(16) SMem sm;

  const int qt = blockIdx.x, bh = blockIdx.y;
  const size_t base = (size_t)bh * Sn * Dn;
  const float* Qb = Qm + base;
  const float* Kb = Km + base;
  const float* Vb = Vm + base;
  float*       Ob = Om + base;

  const int tid  = threadIdx.x;
  const int wv   = tid >> 6, lane = tid & 63;
  const int il   = lane & 31, hi = lane >> 5;
  const int qrow = qt * QB + wv * 32 + il;

  // ---- Q fragments (B-operand: col=lane&31=q, k=hi*8+j), pre-scaled ----
  short8 qf[4];
#pragma unroll
  for (int ks = 0; ks < 4; ++ks) {
    const float4* qp = (const float4*)(Qb + (size_t)qrow * Dn + ks * 16 + hi * 8);
    float4 a = qp[0], b = qp[1];
    a.x*=QSC; a.y*=QSC; a.z*=QSC; a.w*=QSC;
    b.x*=QSC; b.y*=QSC; b.z*=QSC; b.w*=QSC;
    qf[ks] = pack8(a, b);
  }

  float m_run = -1e30f, l_run = 0.f;
  f32x16 acc[2];
#pragma unroll
  for (int r = 0; r < 16; ++r) { acc[0][r] = 0.f; acc[1][r] = 0.f; }

  // staging thread mapping (512 threads stage 64x64 K and 64x64 V^T)
  const int krow = tid >> 3, kcol = (tid & 7) * 8;
  const int vd   = tid & 63, vkc  = (tid >> 6) * 8;

  // ---- prologue: stage tile 0 into buf 0 ----
  {
    const float4* kp = (const float4*)(Kb + (size_t)krow * Dn + kcol);
    float4 ka = kp[0], kb2 = kp[1];
    float vv[8];
#pragma unroll
    for (int j = 0; j < 8; ++j) vv[j] = Vb[(size_t)(vkc + j) * Dn + vd];
    *(short8*)&sm.s.K[0][krow][kcol] = pack8(ka, kb2);
    *(short8*)&sm.s.Vt[0][vd][vkc] = catw(
        cvt_pk_bf16(vv[0], vv[1]), cvt_pk_bf16(vv[2], vv[3]),
        cvt_pk_bf16(vv[4], vv[5]), cvt_pk_bf16(vv[6], vv[7]));
  }
  __syncthreads();

  int cur = 0;
  for (int t = 0; t < NT; ++t) {
    // ---- issue next-tile global loads early (T14: latency hides under compute) ----
    float4 nka, nkb; float nv[8];
    const bool pf = (t + 1 < NT);
    if (pf) {
      const int kv0n = (t + 1) * KVB;
      const float4* kp = (const float4*)(Kb + (size_t)(kv0n + krow) * Dn + kcol);
      nka = kp[0]; nkb = kp[1];
#pragma unroll
      for (int j = 0; j < 8; ++j) nv[j] = Vb[(size_t)(kv0n + vkc + j) * Dn + vd];
    }

    // ---- swapped QK^T: sa[h] = S^T tile, lane holds 32 scores of q=qrow ----
    f32x16 sa[2];
#pragma unroll
    for (int h = 0; h < 2; ++h) {
#pragma unroll
      for (int r = 0; r < 16; ++r) sa[h][r] = 0.f;
#pragma unroll
      for (int ks = 0; ks < 4; ++ks) {
        short8 kf = *(const short8*)&sm.s.K[cur][h * 32 + il][ks * 16 + hi * 8];
        sa[h] = __builtin_amdgcn_mfma_f32_32x32x16_bf16(kf, qf[ks], sa[h], 0, 0, 0);
      }
    }

    // ---- in-register online softmax (31 fmax + 1 cross-half shuffle) ----
    float mx = sa[0][0];
#pragma unroll
    for (int h = 0; h < 2; ++h)
#pragma unroll
      for (int r = 0; r < 16; ++r) mx = fmaxf(mx, sa[h][r]);
    mx = fmaxf(mx, __shfl_xor(mx, 32));
    float mnew = fmaxf(m_run, mx);
    float corr = __builtin_amdgcn_exp2f(m_run - mnew);
    float ls = 0.f;
#pragma unroll
    for (int h = 0; h < 2; ++h)
#pragma unroll
      for (int r = 0; r < 16; ++r) {
        float p = __builtin_amdgcn_exp2f(sa[h][r] - mnew);
        sa[h][r] = p; ls += p;
      }
    ls += __shfl_xor(ls, 32);
    l_run = l_run * corr + ls;
    m_run = mnew;
#pragma unroll
    for (int dt = 0; dt < 2; ++dt)
#pragma unroll
      for (int r = 0; r < 16; ++r) acc[dt][r] *= corr;

    // ---- swapped PV: acc[dt] = O^T; V A-frags read in P's natural kv order ----
    // P row r at lane(hi): kv = (r&3) + 8*(r>>2) + 4*hi (+32h). B-words w0..w7 are
    // consecutive p-pairs; matching V reads are two b64s at kv0 = {4hi, 8+4hi} (+16 for slot 1).
#pragma unroll
    for (int h = 0; h < 2; ++h) {
      unsigned w0 = cvt_pk_bf16(sa[h][0],  sa[h][1]);
      unsigned w1 = cvt_pk_bf16(sa[h][2],  sa[h][3]);
      unsigned w2 = cvt_pk_bf16(sa[h][4],  sa[h][5]);
      unsigned w3 = cvt_pk_bf16(sa[h][6],  sa[h][7]);
      unsigned w4 = cvt_pk_bf16(sa[h][8],  sa[h][9]);
      unsigned w5 = cvt_pk_bf16(sa[h][10], sa[h][11]);
      unsigned w6 = cvt_pk_bf16(sa[h][12], sa[h][13]);
      unsigned w7 = cvt_pk_bf16(sa[h][14], sa[h][15]);
      short8 pb0 = catw(w0, w1, w2, w3);
      short8 pb1 = catw(w4, w5, w6, w7);
#pragma unroll
      for (int dt = 0; dt < 2; ++dt) {
        const short* vrow = &sm.s.Vt[cur][dt * 32 + il][h * 32];
        short8 va = cat4(*(const short4v*)(vrow + 4 * hi),
                         *(const short4v*)(vrow + 8 + 4 * hi));
        acc[dt] = __builtin_amdgcn_mfma_f32_32x32x16_bf16(va, pb0, acc[dt], 0, 0, 0);
        short8 vb = cat4(*(const short4v*)(vrow + 16 + 4 * hi),
                         *(const short4v*)(vrow + 24 + 4 * hi));
        acc[dt] = __builtin_amdgcn_mfma_f32_32x32x16_bf16(vb, pb1, acc[dt], 0, 0, 0);
      }
    }

    // ---- write prefetched tile to the other buffer; single barrier per iter ----
    if (pf) {
      *(short8*)&sm.s.K[cur ^ 1][krow][kcol] = pack8(nka, nkb);
      *(short8*)&sm.s.Vt[cur ^ 1][vd][vkc] = catw(
          cvt_pk_bf16(nv[0], nv[1]), cvt_pk_bf16(nv[2], nv[3]),
          cvt_pk_bf16(nv[4], nv[5]), cvt_pk_bf16(nv[6], nv[7]));
    }
    __syncthreads();
    cur ^= 1;
  }

  // ---- epilogue: normalize, transpose via per-wave LDS slice, coalesced stores ----
  const float inv = 1.0f / l_run;
  const int q2 = lane >> 1, dh = (lane & 1) * 16;
#pragma unroll
  for (int dt = 0; dt < 2; ++dt) {
#pragma unroll
    for (int r = 0; r < 16; ++r) {
      int dcol = (r & 3) + 8 * (r >> 2) + 4 * hi;
      sm.ep[wv][il][dcol] = acc[dt][r] * inv;   // acc[dt][r] = O[qrow][dt*32+dcol]
    }
    // same-wave ds_write -> ds_read: compiler orders via lgkmcnt (may-alias LDS)
#pragma unroll
    for (int i = 0; i < 4; ++i) {
      float4 o = *(const float4*)&sm.ep[wv][q2][dh + i * 4];
      *(float4*)(Ob + (size_t)(qt * QB + wv * 32 + q2) * Dn + dt * 32 + dh + i * 4) = o;
    }
  }
}

extern "C" void kernel_launch(void* const* d_in, const int* in_sizes, int n_in,
                              void* d_out, int out_size, void* d_ws, size_t ws_size,
                              hipStream_t stream) {
  const float* Q = (const float*)d_in[0];
  const float* K = (const float*)d_in[1];
  const float* V = (const float*)d_in[2];
  float* O = (float*)d_out;
  dim3 grid(Sn / QB, 4 * 16);   // (q-tiles, B*H)
  attn_fwd<<<grid, 512, 0, stream>>>(Q, K, V, O);
}

// Round 3
// 99.517 us; speedup vs baseline: 3.4486x; 1.0846x over previous
//
#include <hip/hip_runtime.h>
#include <hip/hip_bf16.h>

typedef __attribute__((ext_vector_type(8))) short short8;
typedef __attribute__((ext_vector_type(4))) short short4v;
typedef __attribute__((ext_vector_type(16))) float f32x16;

constexpr int Sn = 2048, Dn = 64;
constexpr int KVB = 64;          // kv tile
constexpr int QB  = 256;         // 4 waves * 64 q rows
constexpr int NT  = Sn / KVB;    // 32 tiles
constexpr int KSTR = 72;         // 144B rows: b128 K-frag reads conflict-free
constexpr int VSTR = 68;         // 136B rows: bank shift 2 dw/row -> b64 V reads conflict-free
constexpr float QSC = 0.18033688011112042f;  // (1/sqrt(64)) * log2(e)
constexpr float DTH = 8.0f;                  // defer-max threshold (exp2 domain)

struct SMemS { short K[2][KVB][KSTR]; short Vt[2][Dn][VSTR]; };  // 35840 B
union  SMem  { SMemS s; float ep[4][32][36]; };                  // ep aliases K region only

__device__ inline unsigned cvt_pk_bf16(float a, float b) {
  unsigned r;
  asm("v_cvt_pk_bf16_f32 %0, %1, %2" : "=v"(r) : "v"(a), "v"(b));
  return r;
}
__device__ inline short8 catw(unsigned a, unsigned b, unsigned c, unsigned d) {
  union { unsigned u[4]; short8 s; } t;
  t.u[0]=a; t.u[1]=b; t.u[2]=c; t.u[3]=d;
  return t.s;
}
__device__ inline short8 pack8(float4 a, float4 b) {
  return catw(cvt_pk_bf16(a.x,a.y), cvt_pk_bf16(a.z,a.w),
              cvt_pk_bf16(b.x,b.y), cvt_pk_bf16(b.z,b.w));
}
__device__ inline short8 cat4(short4v a, short4v b) {
  short8 r;
  r[0]=a[0]; r[1]=a[1]; r[2]=a[2]; r[3]=a[3];
  r[4]=b[0]; r[5]=b[1]; r[6]=b[2]; r[7]=b[3];
  return r;
}

__global__ __launch_bounds__(256, 2)
void attn_fwd(const float* __restrict__ Qm, const float* __restrict__ Km,
              const float* __restrict__ Vm, float* __restrict__ Om) {
  __shared__ alignas(16) SMem sm;

  // XCD-aware swizzle: co-locate all 8 q-tiles of one bh on one XCD (512 blocks, 512%8==0)
  const int fid = blockIdx.x + (blockIdx.y << 3);
  const int xcd = fid & 7, w = fid >> 3;
  const int qt = w & 7, bh = (xcd << 3) | (w >> 3);

  const size_t base = (size_t)bh * Sn * Dn;
  const float* Qb = Qm + base;
  const float* Kb = Km + base;
  const float* Vb = Vm + base;
  float*       Ob = Om + base;

  const int tid = threadIdx.x, wv = tid >> 6, lane = tid & 63;
  const int il = lane & 31, hi = lane >> 5;
  const int qr0 = qt * QB + wv * 64;

  // ---- Q fragments (B-operand), pre-scaled; two q-halves u=0,1 ----
  short8 qf[2][4];
#pragma unroll
  for (int u = 0; u < 2; ++u)
#pragma unroll
    for (int ks = 0; ks < 4; ++ks) {
      const float4* qp = (const float4*)(Qb + (size_t)(qr0 + u*32 + il) * Dn + ks*16 + hi*8);
      float4 a = qp[0], b = qp[1];
      a.x*=QSC; a.y*=QSC; a.z*=QSC; a.w*=QSC;
      b.x*=QSC; b.y*=QSC; b.z*=QSC; b.w*=QSC;
      qf[u][ks] = pack8(a, b);
    }

  f32x16 acc[2][2];
#pragma unroll
  for (int u = 0; u < 2; ++u)
#pragma unroll
    for (int dt = 0; dt < 2; ++dt)
#pragma unroll
      for (int r = 0; r < 16; ++r) acc[u][dt][r] = 0.f;
  float m_run[2] = {-1e30f, -1e30f}, l_run[2] = {0.f, 0.f};

  // staging mapping (256 threads; 64x64 K + 64x64 Vt per tile)
  const int krow = tid >> 2, kc = (tid & 3) * 16;   // K: 16 cols per thread
  const int vd = tid & 63, vk0 = (tid >> 6) * 8;    // Vt: chunks vk0, vk0+32

  auto stageK = [&](int buf, float4 a0, float4 a1, float4 a2, float4 a3) {
    *(short8*)&sm.s.K[buf][krow][kc]     = pack8(a0, a1);
    *(short8*)&sm.s.K[buf][krow][kc + 8] = pack8(a2, a3);
  };
  auto stageV = [&](int buf, const float* vv) {
#pragma unroll
    for (int c = 0; c < 2; ++c) {
      union { unsigned u[2]; short4v s; } t0, t1;
      t0.u[0] = cvt_pk_bf16(vv[c*8+0], vv[c*8+1]);
      t0.u[1] = cvt_pk_bf16(vv[c*8+2], vv[c*8+3]);
      t1.u[0] = cvt_pk_bf16(vv[c*8+4], vv[c*8+5]);
      t1.u[1] = cvt_pk_bf16(vv[c*8+6], vv[c*8+7]);
      short* p = &sm.s.Vt[buf][vd][vk0 + c*32];
      *(short4v*)p       = t0.s;
      *(short4v*)(p + 4) = t1.s;
    }
  };

  // ---- prologue: stage tile 0 ----
  {
    const float4* kp = (const float4*)(Kb + (size_t)krow * Dn + kc);
    float4 a0 = kp[0], a1 = kp[1], a2 = kp[2], a3 = kp[3];
    float vv[16];
#pragma unroll
    for (int c = 0; c < 2; ++c)
#pragma unroll
      for (int j = 0; j < 8; ++j) vv[c*8+j] = Vb[(size_t)(vk0 + c*32 + j) * Dn + vd];
    stageK(0, a0, a1, a2, a3);
    stageV(0, vv);
  }
  __syncthreads();

  int cur = 0;
  for (int t = 0; t < NT; ++t) {
    const bool pf = (t + 1 < NT);
    float4 na0, na1, na2, na3; float nv[16];
    if (pf) {   // T14: issue next-tile loads early; write after softmax
      const int kvn = (t + 1) * KVB;
      const float4* kp = (const float4*)(Kb + (size_t)(kvn + krow) * Dn + kc);
      na0 = kp[0]; na1 = kp[1]; na2 = kp[2]; na3 = kp[3];
#pragma unroll
      for (int c = 0; c < 2; ++c)
#pragma unroll
        for (int j = 0; j < 8; ++j) nv[c*8+j] = Vb[(size_t)(kvn + vk0 + c*32 + j) * Dn + vd];
    }

    // K fragments once, shared by both q-halves
    short8 kf[2][4];
#pragma unroll
    for (int h = 0; h < 2; ++h)
#pragma unroll
      for (int ks = 0; ks < 4; ++ks)
        kf[h][ks] = *(const short8*)&sm.s.K[cur][h*32 + il][ks*16 + hi*8];

    short8 pb[2][2][2];   // [u][h][slot]
#pragma unroll
    for (int u = 0; u < 2; ++u) {
      f32x16 sa[2];
#pragma unroll
      for (int h = 0; h < 2; ++h) {
#pragma unroll
        for (int r = 0; r < 16; ++r) sa[h][r] = 0.f;
#pragma unroll
        for (int ks = 0; ks < 4; ++ks)
          sa[h] = __builtin_amdgcn_mfma_f32_32x32x16_bf16(kf[h][ks], qf[u][ks], sa[h], 0, 0, 0);
      }
      // in-register online softmax with defer-max (T13)
      float mx = sa[0][0];
#pragma unroll
      for (int h = 0; h < 2; ++h)
#pragma unroll
        for (int r = 0; r < 16; ++r) mx = fmaxf(mx, sa[h][r]);
      mx = fmaxf(mx, __shfl_xor(mx, 32));
      if (__any(mx > m_run[u] + DTH)) {
        float mnew = fmaxf(m_run[u], mx);
        float corr = __builtin_amdgcn_exp2f(m_run[u] - mnew);
        l_run[u] *= corr;
#pragma unroll
        for (int dt = 0; dt < 2; ++dt)
#pragma unroll
          for (int r = 0; r < 16; ++r) acc[u][dt][r] *= corr;
        m_run[u] = mnew;
      }
      const float m0 = m_run[u];
      float ls = 0.f;
#pragma unroll
      for (int h = 0; h < 2; ++h)
#pragma unroll
        for (int r = 0; r < 16; ++r) {
          float p = __builtin_amdgcn_exp2f(sa[h][r] - m0);
          sa[h][r] = p; ls += p;
        }
      ls += __shfl_xor(ls, 32);
      l_run[u] += ls;
#pragma unroll
      for (int h = 0; h < 2; ++h) {
        pb[u][h][0] = catw(cvt_pk_bf16(sa[h][0],  sa[h][1]),  cvt_pk_bf16(sa[h][2],  sa[h][3]),
                           cvt_pk_bf16(sa[h][4],  sa[h][5]),  cvt_pk_bf16(sa[h][6],  sa[h][7]));
        pb[u][h][1] = catw(cvt_pk_bf16(sa[h][8],  sa[h][9]),  cvt_pk_bf16(sa[h][10], sa[h][11]),
                           cvt_pk_bf16(sa[h][12], sa[h][13]), cvt_pk_bf16(sa[h][14], sa[h][15]));
      }
    }

    // write prefetched tile into the other buffer (covered HBM latency above)
    if (pf) { stageK(cur ^ 1, na0, na1, na2, na3); stageV(cur ^ 1, nv); }

    // ---- swapped PV: V A-frags read in P's natural kv order, shared by both halves ----
#pragma unroll
    for (int h = 0; h < 2; ++h)
#pragma unroll
      for (int dt = 0; dt < 2; ++dt) {
        const short* vrow = &sm.s.Vt[cur][dt*32 + il][h*32];
        short8 va = cat4(*(const short4v*)(vrow + 4*hi),      *(const short4v*)(vrow + 8  + 4*hi));
        short8 vb = cat4(*(const short4v*)(vrow + 16 + 4*hi), *(const short4v*)(vrow + 24 + 4*hi));
#pragma unroll
        for (int u = 0; u < 2; ++u) {
          acc[u][dt] = __builtin_amdgcn_mfma_f32_32x32x16_bf16(va, pb[u][h][0], acc[u][dt], 0, 0, 0);
          acc[u][dt] = __builtin_amdgcn_mfma_f32_32x32x16_bf16(vb, pb[u][h][1], acc[u][dt], 0, 0, 0);
        }
      }
    __syncthreads();
    cur ^= 1;
  }

  // ---- epilogue: normalize, transpose via per-wave LDS slice, coalesced stores ----
  const int q2 = lane >> 1, dh = (lane & 1) * 16;
#pragma unroll
  for (int u = 0; u < 2; ++u) {
    const float inv = 1.0f / l_run[u];
#pragma unroll
    for (int dt = 0; dt < 2; ++dt) {
#pragma unroll
      for (int r = 0; r < 16; ++r) {
        int dcol = (r & 3) + 8 * (r >> 2) + 4 * hi;
        sm.ep[wv][il][dcol] = acc[u][dt][r] * inv;
      }
#pragma unroll
      for (int i = 0; i < 4; ++i) {
        float4 o = *(const float4*)&sm.ep[wv][q2][dh + i*4];
        *(float4*)(Ob + (size_t)(qr0 + u*32 + q2) * Dn + dt*32 + dh + i*4) = o;
      }
    }
  }
}

extern "C" void kernel_launch(void* const* d_in, const int* in_sizes, int n_in,
                              void* d_out, int out_size, void* d_ws, size_t ws_size,
                              hipStream_t stream) {
  const float* Q = (const float*)d_in[0];
  const float* K = (const float*)d_in[1];
  const float* V = (const float*)d_in[2];
  float* O = (float*)d_out;
  dim3 grid(Sn / QB, 4 * 16);   // (q-tiles, B*H), swizzled in-kernel
  attn_fwd<<<grid, 256, 0, stream>>>(Q, K, V, O);
}